// Round 2
// baseline (541.522 us; speedup 1.0000x reference)
//
#include <hip/hip_runtime.h>
#include <math.h>

#define B_   8
#define C_   256
#define HW_  4096
#define N_   32768   // B_*HW_
#define M_   2024
#define MP_  2048    // M padded to multiple of 64
#define CH_  64
#define NCHUNK (MP_ / 64)  // 32
#define INV_TEMP 33.333333333333336f
#define NEPS 1e-12f

typedef __attribute__((ext_vector_type(8))) short short8;   // 8 x bf16 (4 VGPRs)
typedef __attribute__((ext_vector_type(4))) float floatx4;  // MFMA accumulator

__device__ __forceinline__ float wred64(float s) {
#pragma unroll
  for (int off = 32; off > 0; off >>= 1) s += __shfl_xor(s, off, 64);
  return s;
}

__device__ __forceinline__ unsigned short f2bf(float f) {
  union { float f; unsigned u; } v; v.f = f;
  unsigned r = v.u + 0x7FFFu + ((v.u >> 16) & 1u);  // RNE, finite inputs only
  return (unsigned short)(r >> 16);
}
__device__ __forceinline__ float bf2f(unsigned short b) {
  union { unsigned u; float f; } v; v.u = ((unsigned)b) << 16; return v.f;
}

// raw workgroup barrier that does NOT drain vmcnt (keeps global_load_lds
// prefetch in flight across it) — CK/AITER idiom.
__device__ __forceinline__ void barrier_lds_only() {
  asm volatile("s_waitcnt lgkmcnt(0)\n\ts_barrier" ::: "memory");
}

// async 16B/lane global->LDS copy; LDS dest = wave-uniform base + lane*16.
__device__ __forceinline__ void async_copy16(const unsigned short* gsrc,
                                             unsigned short* lds) {
  __builtin_amdgcn_global_load_lds(
      (const __attribute__((address_space(1))) void*)gsrc,
      (__attribute__((address_space(3))) void*)lds, 16, 0, 0);
}

// ---- normalize memory rows -> memS (MFMA B-frag order) + membT [C][MP] ----
// memS element (m, c): unit = ((m>>6)*32 + (c>>5)*4 + ((c>>3)&3))*64 + (m&63),
// u16 index = unit*8 + (c&7). A 64-row chunk is a contiguous 32 KB block that
// the flash kernel copies to LDS verbatim via global_load_lds.
__global__ __launch_bounds__(256) void norm_mem_kernel(
    const float* __restrict__ fg, const float* __restrict__ bg,
    unsigned short* __restrict__ fgS, unsigned short* __restrict__ bgS,
    unsigned short* __restrict__ fgT, unsigned short* __restrict__ bgT) {
  __shared__ unsigned short tile[64][258];
  int bid = blockIdx.x;  // 0..63: 32 fg chunks then 32 bg chunks
  const float* src; unsigned short *ms, *mt; int r0;
  if (bid < 32) { src = fg; ms = fgS; mt = fgT; r0 = bid * 64; }
  else          { src = bg; ms = bgS; mt = bgT; r0 = (bid - 32) * 64; }
  int t = threadIdx.x;
  int rr = t >> 2, c4 = t & 3;  // row r0+rr, channel quarter c4
  int row = r0 + rr;
  int chunk = r0 >> 6;
  float v[64];
  float s = 0.f;
  if (row < M_) {
    const float4* p = (const float4*)(src + (size_t)row * C_ + c4 * 64);
#pragma unroll
    for (int i = 0; i < 16; ++i) {
      float4 q = p[i];
      v[i * 4 + 0] = q.x; v[i * 4 + 1] = q.y; v[i * 4 + 2] = q.z; v[i * 4 + 3] = q.w;
      s += q.x * q.x + q.y * q.y + q.z * q.z + q.w * q.w;
    }
  } else {
#pragma unroll
    for (int i = 0; i < 64; ++i) v[i] = 0.f;  // zero padding rows
  }
  s += __shfl_xor(s, 1, 64);
  s += __shfl_xor(s, 2, 64);
  float inv = (row < M_) ? 1.0f / fmaxf(sqrtf(s), NEPS) : 0.f;
#pragma unroll
  for (int i = 0; i < 16; ++i) {
    int c = c4 * 64 + i * 4;
    ushort4 o;
    o.x = f2bf(v[i * 4 + 0] * inv); o.y = f2bf(v[i * 4 + 1] * inv);
    o.z = f2bf(v[i * 4 + 2] * inv); o.w = f2bf(v[i * 4 + 3] * inv);
    int unit = (chunk * 32 + (c >> 5) * 4 + ((c >> 3) & 3)) * 64 + rr;
    *(ushort4*)&ms[(size_t)unit * 8 + (c & 7)] = o;
    *(ushort4*)&tile[rr][c] = o;
  }
  __syncthreads();
  int m = t & 63, cw = t >> 6;
#pragma unroll 8
  for (int j = 0; j < 64; ++j) {
    int c = cw * 64 + j;
    mt[(size_t)c * MP_ + r0 + m] = tile[m][c];
  }
}

// ---- fused per-pixel inv-norm + xnb bf16 [N,C] build (one feats pass) ----
__global__ __launch_bounds__(256) void prep_x_kernel(
    const float* __restrict__ feats, float* __restrict__ invn,
    unsigned short* __restrict__ xnb) {
  __shared__ unsigned short tileb[256][66];
  __shared__ float part[4][64];
  __shared__ float invs[64];
  int t = threadIdx.x, hwl = t & 63, cw = t >> 6;
  int n0 = blockIdx.x * 64;
  int b = n0 >> 12, hw0 = n0 & 4095;
  const float* p = feats + (size_t)b * C_ * HW_ + hw0 + hwl;
  float s = 0.f;
#pragma unroll 8
  for (int i = 0; i < 64; ++i) {
    int c = cw * 64 + i;
    float v = p[(size_t)c * HW_];
    s += v * v;
    tileb[c][hwl] = f2bf(v);
  }
  part[cw][hwl] = s;
  __syncthreads();
  if (t < 64) {
    float tot = part[0][t] + part[1][t] + part[2][t] + part[3][t];
    float inv = 1.0f / fmaxf(sqrtf(tot), NEPS);
    invn[n0 + t] = inv;
    invs[t] = inv;
  }
  __syncthreads();
  int px = t >> 2, q = t & 3;
  float iv = invs[px];
  unsigned short* xp = xnb + (size_t)(n0 + px) * C_;
#pragma unroll
  for (int blk = 0; blk < 8; ++blk) {
    int cb = blk * 4 + q;  // 4 q-lanes -> 64 B contiguous stores
    short8 o;
#pragma unroll
    for (int j = 0; j < 8; ++j)
      o[j] = (short)f2bf(bf2f(tileb[cb * 8 + j][px]) * iv);
    *(short8*)&xp[cb * 8] = o;
  }
}

// ---------------- gates: 16 pixels per block ----------------
__global__ __launch_bounds__(256) void gate_kernel(
    const unsigned short* __restrict__ xnb,
    const float* __restrict__ w1f, const float* __restrict__ b1f,
    const float* __restrict__ w2f, const float* __restrict__ b2f,
    const float* __restrict__ w1b, const float* __restrict__ b1b,
    const float* __restrict__ w2b, const float* __restrict__ b2b,
    float* __restrict__ gf, float* __restrict__ gb) {
  __shared__ float xr[16][C_];
  int t = threadIdx.x, w = t >> 6, lane = t & 63;
  int n0 = blockIdx.x * 16;
#pragma unroll
  for (int pp = 0; pp < 4; ++pp) {
    int px = w * 4 + pp;
    ushort4 u = *(const ushort4*)&xnb[(size_t)(n0 + px) * C_ + lane * 4];
    xr[px][lane * 4 + 0] = bf2f(u.x);
    xr[px][lane * 4 + 1] = bf2f(u.y);
    xr[px][lane * 4 + 2] = bf2f(u.z);
    xr[px][lane * 4 + 3] = bf2f(u.w);
  }
  __syncthreads();
  float hf[4], hb[4];
#pragma unroll
  for (int pp = 0; pp < 4; ++pp) { hf[pp] = b1f[lane]; hb[pp] = b1b[lane]; }
#pragma unroll 4
  for (int c = 0; c < C_; ++c) {
    float wf = w1f[c * CH_ + lane];
    float wb = w1b[c * CH_ + lane];
#pragma unroll
    for (int pp = 0; pp < 4; ++pp) {
      float x = xr[w * 4 + pp][c];
      hf[pp] += x * wf;
      hb[pp] += x * wb;
    }
  }
  float b2fv = b2f[0], b2bv = b2b[0];
#pragma unroll
  for (int pp = 0; pp < 4; ++pp) {
    float sf = fmaxf(hf[pp], 0.f) * w2f[lane];
    float sb = fmaxf(hb[pp], 0.f) * w2b[lane];
    sf = wred64(sf);
    sb = wred64(sb);
    if (lane == 0) {
      gf[n0 + w * 4 + pp] = 1.f / (1.f + __expf(-(sf + b2fv)));
      gb[n0 + w * 4 + pp] = 1.f / (1.f + __expf(-(sb + b2bv)));
    }
  }
}

// stage one 32 KB memS chunk into mtile (contiguous copy, no VGPR round-trip)
__device__ __forceinline__ void stage_chunk(const unsigned short* memS, int mc,
                                            unsigned short* mtile, int w, int l) {
  const unsigned short* src = memS + (size_t)mc * 16384;
#pragma unroll
  for (int it = 0; it < 4; ++it) {
    int seg = (it * 8 + w) * 512;  // u16 units; 64 lanes x 16 B = 1 KB/wave/iter
    async_copy16(src + seg + l * 8, mtile + seg);
  }
}

// ---------------- fused MFMA flash attention v6 ----------------
// 64 pixels/block, 8 waves, 2 blocks/CU.
// Wave mapping (mq=w&3 -> m-rows mq*16.., ph=w>>2 -> pixel half). Each wave
// holds TWO 16-pixel A-tiles (afrag[2][8]) and computes a 32x16 S tile, so
// each mtile B-frag read feeds 2 MFMAs (S-phase LDS reads halved vs v4:
// 256KB -> 128KB per chunk per CU). P-phase: exp via fma+(-1e30 bias) mask
// (bit-exact vs select); bf16 via the v4-verified scalar f2bf (v5's
// v_cvt_pk_bf16_f32 asm was the prime suspect for the absmax failure —
// reverted). bfT loads post-P-store (pre-barrier); P single-buffered
// (write->read ordering barrier-enforced); setprio(1) around MFMA clusters.
__global__ __launch_bounds__(512, 4) void flash_fused_kernel(
    const unsigned short* __restrict__ xnb,
    const unsigned short* __restrict__ fgS, const unsigned short* __restrict__ fgT,
    const unsigned short* __restrict__ bgS, const unsigned short* __restrict__ bgT,
    const float* __restrict__ gf, const float* __restrict__ gb,
    const float* __restrict__ feats, const float* __restrict__ invn,
    float* __restrict__ out) {
  __shared__ __align__(16) char smem[41472];
  unsigned short* mtile = (unsigned short*)smem;            // 32 KB frag-order chunk
  unsigned short* Pbuf  = (unsigned short*)(smem + 32768);  // 8 KB, single buffer
  float* rowsum = (float*)(smem + 40960);                   // [64]
  float* comb   = (float*)(smem + 41216);                   // [64]
  float* trans  = (float*)smem;                             // [64][67] f32, aliases mtile

  int t = threadIdx.x;
  int w = t >> 6, l = t & 63;
  int lm = l & 15, quad = l >> 4;
  int mq = w & 3, ph = w >> 2;
  int row0 = blockIdx.x * 64;

  // A-frags: 2 pixel tiles, rows row0 + ph*32 + at*16 + lm
  short8 afrag[2][8];
  {
    const unsigned short* ap = xnb + (size_t)(row0 + ph * 32 + lm) * C_ + quad * 8;
#pragma unroll
    for (int at = 0; at < 2; ++at)
#pragma unroll
      for (int kb = 0; kb < 8; ++kb)
        afrag[at][kb] = *(const short8*)(ap + at * 16 * C_ + kb * 32);
  }

  // LDS address bases (u16 units)
  int mb = (quad * 64 + mq * 16 + lm) * 8;                              // S B-frag read
  int wb = ((mq * 2 + (lm >> 3)) * 64 + ph * 32 + quad * 4) * 8 + (lm & 7);  // P write
  int rb = (quad * 64 + lm) * 8;                                       // P A-frag read

#pragma unroll 1
  for (int pass = 0; pass < 2; ++pass) {
    const unsigned short* memS  = pass ? bgS : fgS;
    const unsigned short* membT = pass ? bgT : fgT;
    const float* gp = pass ? gb : gf;

    floatx4 accO[4][2];
#pragma unroll
    for (int rt = 0; rt < 4; ++rt)
#pragma unroll
      for (int ct = 0; ct < 2; ++ct) accO[rt][ct] = (floatx4){0.f, 0.f, 0.f, 0.f};
    float rs[2][4];
#pragma unroll
    for (int at = 0; at < 2; ++at)
#pragma unroll
      for (int r = 0; r < 4; ++r) rs[at][r] = 0.f;
    if (t < 64) rowsum[t] = 0.f;  // ordered before atomics by chunk barriers

    stage_chunk(memS, 0, mtile, w, l);

#pragma unroll 1
    for (int mc = 0; mc < NCHUNK; ++mc) {
      __syncthreads();  // A: drains vmcnt -> mtile[mc] ready for all waves

      // exp-mask bias: padding rows get exp(-1e30) = 0 (no cndmask per elem);
      // for valid rows fma(S,IT,0) == rn(S*IT) — bit-exact vs v4.
      float ebias = (mc * 64 + mq * 16 + lm < M_) ? 0.f : -1e30f;

      // ---- S = Q @ mem^T: 2 pixel-tiles x 1 mrow-tile, B-frag reused 2x ----
      floatx4 accS[2];
      accS[0] = (floatx4){0.f, 0.f, 0.f, 0.f};
      accS[1] = (floatx4){0.f, 0.f, 0.f, 0.f};
      __builtin_amdgcn_s_setprio(1);
#pragma unroll
      for (int kb = 0; kb < 8; ++kb) {
        short8 bf = *(const short8*)&mtile[mb + kb * 2048];
        accS[0] = __builtin_amdgcn_mfma_f32_16x16x32_bf16(afrag[0][kb], bf, accS[0], 0, 0, 0);
        accS[1] = __builtin_amdgcn_mfma_f32_16x16x32_bf16(afrag[1][kb], bf, accS[1], 0, 0, 0);
      }
      __builtin_amdgcn_s_setprio(0);

      // ---- P = exp(S/T) bf16 (unnormalized), A-frag-order store ----
      // scalar f2bf path (v4-verified numerics: rowsum accumulates the
      // rounded bf16 value so denominator matches the PV numerator)
#pragma unroll
      for (int at = 0; at < 2; ++at) {
#pragma unroll
        for (int r = 0; r < 4; ++r) {
          float pv = __expf(__builtin_fmaf(accS[at][r], INV_TEMP, ebias));
          unsigned short pb = f2bf(pv);
          rs[at][r] += bf2f(pb);
          Pbuf[wb + at * 128 + r * 8] = pb;
        }
      }

      // PV B-frags (global/L2, read-once) — issued pre-barrier so the L2
      // latency hides under barrier + stage + P-reads
      short8 bfT[2][2];
#pragma unroll
      for (int ct = 0; ct < 2; ++ct) {
        const unsigned short* tp =
            membT + (size_t)(w * 32 + ct * 16 + lm) * MP_ + mc * 64 + quad * 8;
        bfT[ct][0] = *(const short8*)(tp);
        bfT[ct][1] = *(const short8*)(tp + 32);
      }

      barrier_lds_only();  // B: P visible + mtile S-reads done (vmcnt NOT drained)

      // issue next chunk's async stage (in flight across PV, lands before next A)
      if (mc + 1 < NCHUNK) stage_chunk(memS, mc + 1, mtile, w, l);

      // ---- O += P @ mem (this wave's 32-wide C-slice) ----
      __builtin_amdgcn_s_setprio(1);
#pragma unroll
      for (int rt = 0; rt < 4; ++rt) {
        short8 pf0 = *(const short8*)&Pbuf[rb + rt * 128];
        accO[rt][0] = __builtin_amdgcn_mfma_f32_16x16x32_bf16(pf0, bfT[0][0], accO[rt][0], 0, 0, 0);
        accO[rt][1] = __builtin_amdgcn_mfma_f32_16x16x32_bf16(pf0, bfT[1][0], accO[rt][1], 0, 0, 0);
        short8 pf1 = *(const short8*)&Pbuf[rb + rt * 128 + 2048];
        accO[rt][0] = __builtin_amdgcn_mfma_f32_16x16x32_bf16(pf1, bfT[0][1], accO[rt][0], 0, 0, 0);
        accO[rt][1] = __builtin_amdgcn_mfma_f32_16x16x32_bf16(pf1, bfT[1][1], accO[rt][1], 0, 0, 0);
      }
      __builtin_amdgcn_s_setprio(0);
    }

    // ---- rowsum: intra-wave shuffle over lm, cross-wave LDS atomic ----
#pragma unroll
    for (int off = 1; off < 16; off <<= 1)
#pragma unroll
      for (int at = 0; at < 2; ++at)
#pragma unroll
        for (int r = 0; r < 4; ++r) rs[at][r] += __shfl_xor(rs[at][r], off, 64);
    if (lm == 0) {
#pragma unroll
      for (int at = 0; at < 2; ++at)
#pragma unroll
        for (int r = 0; r < 4; ++r)
          atomicAdd(&rowsum[ph * 32 + at * 16 + quad * 4 + r], rs[at][r]);
    }
    __syncthreads();
    if (t < 64) comb[t] = gp[row0 + t] / rowsum[t];
    __syncthreads();

    // ---- epilogue (trans aliases mtile; no stage loads in flight here) ----
    float iv = invn[row0 + l];
    int bb = row0 >> 12, hw0 = row0 & 4095;
    size_t ob = (size_t)bb * (size_t)C_ * HW_ + hw0 + l;
#pragma unroll 1
    for (int cg2 = 0; cg2 < 4; ++cg2) {
      if ((w >> 1) == cg2) {
#pragma unroll
        for (int rt = 0; rt < 4; ++rt)
#pragma unroll
          for (int r = 0; r < 4; ++r) {
            float cf = comb[16 * rt + quad * 4 + r];
#pragma unroll
            for (int ct = 0; ct < 2; ++ct)
              trans[(16 * rt + quad * 4 + r) * 67 + (w & 1) * 32 + ct * 16 + lm] =
                  cf * accO[rt][ct][r];
          }
      }
      __syncthreads();
      if (pass == 0) {
#pragma unroll
        for (int i = 0; i < 8; ++i) {
          int cl = w * 8 + i;
          int cg = cg2 * 64 + cl;
          out[ob + (size_t)cg * HW_] = trans[l * 67 + cl];  // out = alpha_f * O_f
        }
      } else {
#pragma unroll
        for (int i = 0; i < 8; ++i) {
          int cl = w * 8 + i;
          int cg = cg2 * 64 + cl;
          size_t a = ob + (size_t)cg * HW_;
          out[a] = feats[a] * iv + out[a] - trans[l * 67 + cl];
        }
      }
      __syncthreads();
    }
  }
}

extern "C" void kernel_launch(void* const* d_in, const int* in_sizes, int n_in,
                              void* d_out, int out_size, void* d_ws, size_t ws_size,
                              hipStream_t stream) {
  const float* feats = (const float*)d_in[0];
  const float* fg    = (const float*)d_in[1];
  const float* bg    = (const float*)d_in[2];
  const float* w1f   = (const float*)d_in[3];
  const float* b1f   = (const float*)d_in[4];
  const float* w2f   = (const float*)d_in[5];
  const float* b2f   = (const float*)d_in[6];
  const float* w1b   = (const float*)d_in[7];
  const float* b1b   = (const float*)d_in[8];
  const float* w2b   = (const float*)d_in[9];
  const float* b2b   = (const float*)d_in[10];
  float* out = (float*)d_out;

  char* ws = (char*)d_ws;
  unsigned short* xnb = (unsigned short*)ws;                 // N_*C_ bf16
  unsigned short* fgS = xnb + (size_t)N_ * C_;               // MP_*C_ (frag order)
  unsigned short* bgS = fgS + (size_t)MP_ * C_;
  unsigned short* fgT = bgS + (size_t)MP_ * C_;              // C_*MP_
  unsigned short* bgT = fgT + (size_t)C_ * MP_;
  float* gf   = (float*)(bgT + (size_t)C_ * MP_);            // N_
  float* gb   = gf + N_;                                     // N_
  float* invn = gb + N_;                                     // N_

  norm_mem_kernel<<<64, 256, 0, stream>>>(fg, bg, fgS, bgS, fgT, bgT);
  prep_x_kernel<<<N_ / 64, 256, 0, stream>>>(feats, invn, xnb);
  gate_kernel<<<N_ / 16, 256, 0, stream>>>(xnb, w1f, b1f, w2f, b2f,
                                           w1b, b1b, w2b, b2b, gf, gb);
  flash_fused_kernel<<<N_ / 64, 512, 0, stream>>>(
      xnb, fgS, fgT, bgS, bgT, gf, gb, feats, invn, out);
}

// Round 3
// 350.136 us; speedup vs baseline: 1.5466x; 1.5466x over previous
//
#include <hip/hip_runtime.h>
#include <math.h>

#define B_   8
#define C_   256
#define HW_  4096
#define N_   32768   // B_*HW_
#define M_   2024
#define MP_  2048    // M padded to multiple of 64
#define CH_  64
#define NCHUNK (MP_ / 64)  // 32
#define INV_TEMP 33.333333333333336f
#define NEPS 1e-12f

typedef __attribute__((ext_vector_type(8))) short short8;   // 8 x bf16 (4 VGPRs)
typedef __attribute__((ext_vector_type(4))) float floatx4;  // MFMA accumulator

__device__ __forceinline__ float wred64(float s) {
#pragma unroll
  for (int off = 32; off > 0; off >>= 1) s += __shfl_xor(s, off, 64);
  return s;
}

__device__ __forceinline__ unsigned short f2bf(float f) {
  union { float f; unsigned u; } v; v.f = f;
  unsigned r = v.u + 0x7FFFu + ((v.u >> 16) & 1u);  // RNE, finite inputs only
  return (unsigned short)(r >> 16);
}
__device__ __forceinline__ float bf2f(unsigned short b) {
  union { unsigned u; float f; } v; v.u = ((unsigned)b) << 16; return v.f;
}

// raw workgroup barrier that does NOT drain vmcnt (keeps global_load_lds
// prefetch in flight across it) — CK/AITER idiom.
__device__ __forceinline__ void barrier_lds_only() {
  asm volatile("s_waitcnt lgkmcnt(0)\n\ts_barrier" ::: "memory");
}

// async 16B/lane global->LDS copy; LDS dest = wave-uniform base + lane*16.
__device__ __forceinline__ void async_copy16(const unsigned short* gsrc,
                                             unsigned short* lds) {
  __builtin_amdgcn_global_load_lds(
      (const __attribute__((address_space(1))) void*)gsrc,
      (__attribute__((address_space(3))) void*)lds, 16, 0, 0);
}

// ---- normalize memory rows -> memS (MFMA B-frag order) + membT [C][MP] ----
// memS element (m, c): unit = ((m>>6)*32 + (c>>5)*4 + ((c>>3)&3))*64 + (m&63),
// u16 index = unit*8 + (c&7). A 64-row chunk is a contiguous 32 KB block that
// the flash kernel copies to LDS verbatim via global_load_lds.
__global__ __launch_bounds__(256) void norm_mem_kernel(
    const float* __restrict__ fg, const float* __restrict__ bg,
    unsigned short* __restrict__ fgS, unsigned short* __restrict__ bgS,
    unsigned short* __restrict__ fgT, unsigned short* __restrict__ bgT) {
  __shared__ unsigned short tile[64][258];
  int bid = blockIdx.x;  // 0..63: 32 fg chunks then 32 bg chunks
  const float* src; unsigned short *ms, *mt; int r0;
  if (bid < 32) { src = fg; ms = fgS; mt = fgT; r0 = bid * 64; }
  else          { src = bg; ms = bgS; mt = bgT; r0 = (bid - 32) * 64; }
  int t = threadIdx.x;
  int rr = t >> 2, c4 = t & 3;  // row r0+rr, channel quarter c4
  int row = r0 + rr;
  int chunk = r0 >> 6;
  float v[64];
  float s = 0.f;
  if (row < M_) {
    const float4* p = (const float4*)(src + (size_t)row * C_ + c4 * 64);
#pragma unroll
    for (int i = 0; i < 16; ++i) {
      float4 q = p[i];
      v[i * 4 + 0] = q.x; v[i * 4 + 1] = q.y; v[i * 4 + 2] = q.z; v[i * 4 + 3] = q.w;
      s += q.x * q.x + q.y * q.y + q.z * q.z + q.w * q.w;
    }
  } else {
#pragma unroll
    for (int i = 0; i < 64; ++i) v[i] = 0.f;  // zero padding rows
  }
  s += __shfl_xor(s, 1, 64);
  s += __shfl_xor(s, 2, 64);
  float inv = (row < M_) ? 1.0f / fmaxf(sqrtf(s), NEPS) : 0.f;
#pragma unroll
  for (int i = 0; i < 16; ++i) {
    int c = c4 * 64 + i * 4;
    ushort4 o;
    o.x = f2bf(v[i * 4 + 0] * inv); o.y = f2bf(v[i * 4 + 1] * inv);
    o.z = f2bf(v[i * 4 + 2] * inv); o.w = f2bf(v[i * 4 + 3] * inv);
    int unit = (chunk * 32 + (c >> 5) * 4 + ((c >> 3) & 3)) * 64 + rr;
    *(ushort4*)&ms[(size_t)unit * 8 + (c & 7)] = o;
    *(ushort4*)&tile[rr][c] = o;
  }
  __syncthreads();
  int m = t & 63, cw = t >> 6;
#pragma unroll 8
  for (int j = 0; j < 64; ++j) {
    int c = cw * 64 + j;
    mt[(size_t)c * MP_ + r0 + m] = tile[m][c];
  }
}

// ---- fused per-pixel inv-norm + xnb bf16 [N,C] build (one feats pass) ----
__global__ __launch_bounds__(256) void prep_x_kernel(
    const float* __restrict__ feats, float* __restrict__ invn,
    unsigned short* __restrict__ xnb) {
  __shared__ unsigned short tileb[256][66];
  __shared__ float part[4][64];
  __shared__ float invs[64];
  int t = threadIdx.x, hwl = t & 63, cw = t >> 6;
  int n0 = blockIdx.x * 64;
  int b = n0 >> 12, hw0 = n0 & 4095;
  const float* p = feats + (size_t)b * C_ * HW_ + hw0 + hwl;
  float s = 0.f;
#pragma unroll 8
  for (int i = 0; i < 64; ++i) {
    int c = cw * 64 + i;
    float v = p[(size_t)c * HW_];
    s += v * v;
    tileb[c][hwl] = f2bf(v);
  }
  part[cw][hwl] = s;
  __syncthreads();
  if (t < 64) {
    float tot = part[0][t] + part[1][t] + part[2][t] + part[3][t];
    float inv = 1.0f / fmaxf(sqrtf(tot), NEPS);
    invn[n0 + t] = inv;
    invs[t] = inv;
  }
  __syncthreads();
  int px = t >> 2, q = t & 3;
  float iv = invs[px];
  unsigned short* xp = xnb + (size_t)(n0 + px) * C_;
#pragma unroll
  for (int blk = 0; blk < 8; ++blk) {
    int cb = blk * 4 + q;  // 4 q-lanes -> 64 B contiguous stores
    short8 o;
#pragma unroll
    for (int j = 0; j < 8; ++j)
      o[j] = (short)f2bf(bf2f(tileb[cb * 8 + j][px]) * iv);
    *(short8*)&xp[cb * 8] = o;
  }
}

// ---------------- gates: 16 pixels per block ----------------
__global__ __launch_bounds__(256) void gate_kernel(
    const unsigned short* __restrict__ xnb,
    const float* __restrict__ w1f, const float* __restrict__ b1f,
    const float* __restrict__ w2f, const float* __restrict__ b2f,
    const float* __restrict__ w1b, const float* __restrict__ b1b,
    const float* __restrict__ w2b, const float* __restrict__ b2b,
    float* __restrict__ gf, float* __restrict__ gb) {
  __shared__ float xr[16][C_];
  int t = threadIdx.x, w = t >> 6, lane = t & 63;
  int n0 = blockIdx.x * 16;
#pragma unroll
  for (int pp = 0; pp < 4; ++pp) {
    int px = w * 4 + pp;
    ushort4 u = *(const ushort4*)&xnb[(size_t)(n0 + px) * C_ + lane * 4];
    xr[px][lane * 4 + 0] = bf2f(u.x);
    xr[px][lane * 4 + 1] = bf2f(u.y);
    xr[px][lane * 4 + 2] = bf2f(u.z);
    xr[px][lane * 4 + 3] = bf2f(u.w);
  }
  __syncthreads();
  float hf[4], hb[4];
#pragma unroll
  for (int pp = 0; pp < 4; ++pp) { hf[pp] = b1f[lane]; hb[pp] = b1b[lane]; }
#pragma unroll 4
  for (int c = 0; c < C_; ++c) {
    float wf = w1f[c * CH_ + lane];
    float wb = w1b[c * CH_ + lane];
#pragma unroll
    for (int pp = 0; pp < 4; ++pp) {
      float x = xr[w * 4 + pp][c];
      hf[pp] += x * wf;
      hb[pp] += x * wb;
    }
  }
  float b2fv = b2f[0], b2bv = b2b[0];
#pragma unroll
  for (int pp = 0; pp < 4; ++pp) {
    float sf = fmaxf(hf[pp], 0.f) * w2f[lane];
    float sb = fmaxf(hb[pp], 0.f) * w2b[lane];
    sf = wred64(sf);
    sb = wred64(sb);
    if (lane == 0) {
      gf[n0 + w * 4 + pp] = 1.f / (1.f + __expf(-(sf + b2fv)));
      gb[n0 + w * 4 + pp] = 1.f / (1.f + __expf(-(sb + b2bv)));
    }
  }
}

// stage one 32 KB memS chunk into mtile (contiguous copy, no VGPR round-trip)
__device__ __forceinline__ void stage_chunk(const unsigned short* memS, int mc,
                                            unsigned short* mtile, int w, int l) {
  const unsigned short* src = memS + (size_t)mc * 16384;
#pragma unroll
  for (int it = 0; it < 4; ++it) {
    int seg = (it * 8 + w) * 512;  // u16 units; 64 lanes x 16 B = 1 KB/wave/iter
    async_copy16(src + seg + l * 8, mtile + seg);
  }
}

// ---------------- fused MFMA flash attention v7 ----------------
// = the verified v4 structure (224 us) with two register-neutral additions:
//   (a) exp-mask via fma bias: pv = exp(fma(S, INV_TEMP, ebias)),
//       ebias = -1e30 on padding rows (bit-exact vs cndmask: fma(S,IT,0)
//       = rn(S*IT); exp(-1e30) = 0). Removes one select per P element.
//   (b) s_setprio(1) around both MFMA clusters (T5; phase-split schedule).
// v5/v6's wave remap (afrag[2][8] = 64 VGPR) spilled past the 128-reg cap
// at launch_bounds(512,4): FETCH +92MB / WRITE +35MB of scratch traffic,
// 2x slowdown. Reverted; afrag stays [8] (32 VGPR), bfT at chunk-top
// (long L2-latency window), P double-buffered.
__global__ __launch_bounds__(512, 4) void flash_fused_kernel(
    const unsigned short* __restrict__ xnb,
    const unsigned short* __restrict__ fgS, const unsigned short* __restrict__ fgT,
    const unsigned short* __restrict__ bgS, const unsigned short* __restrict__ bgT,
    const float* __restrict__ gf, const float* __restrict__ gb,
    const float* __restrict__ feats, const float* __restrict__ invn,
    float* __restrict__ out) {
  __shared__ __align__(16) char smem[49664];
  unsigned short* mtile = (unsigned short*)smem;            // 32 KB frag-order chunk
  unsigned short* Pbuf0 = (unsigned short*)(smem + 32768);  // 8 KB: unit=(g*64+prow)
  unsigned short* Pbuf1 = (unsigned short*)(smem + 40960);  // 8 KB
  float* rowsum = (float*)(smem + 49152);                   // [64]
  float* comb   = (float*)(smem + 49408);                   // [64]
  float* trans  = (float*)smem;                             // [64][67] f32, aliases mtile

  int t = threadIdx.x;
  int w = t >> 6, l = t & 63;
  int lm = l & 15, quad = l >> 4;
  int rg = w & 3, mh = w >> 2;
  int row0 = blockIdx.x * 64;

  // A-frags: rows row0 + 16*rg + lm (waves rg and rg+4 duplicate)
  short8 afrag[8];
  {
    const unsigned short* ap = xnb + (size_t)(row0 + 16 * rg + lm) * C_ + quad * 8;
#pragma unroll
    for (int kb = 0; kb < 8; ++kb)
      afrag[kb] = *(const short8*)(ap + kb * 32);
  }

  int bb = row0 >> 12, hw0 = row0 & 4095;
  float iv = invn[row0 + l];
  size_t ob = (size_t)bb * (size_t)C_ * HW_ + hw0 + l;

#pragma unroll 1
  for (int pass = 0; pass < 2; ++pass) {
    const unsigned short* memS  = pass ? bgS : fgS;
    const unsigned short* membT = pass ? bgT : fgT;
    const float* gp = pass ? gb : gf;

    floatx4 accO[4][2];
#pragma unroll
    for (int rt = 0; rt < 4; ++rt)
#pragma unroll
      for (int ct = 0; ct < 2; ++ct) accO[rt][ct] = (floatx4){0.f, 0.f, 0.f, 0.f};
    float rs[4] = {0.f, 0.f, 0.f, 0.f};
    if (t < 64) rowsum[t] = 0.f;  // ordered before atomics by chunk barriers

    stage_chunk(memS, 0, mtile, w, l);

#pragma unroll 1
    for (int mc = 0; mc < NCHUNK; ++mc) {
      __syncthreads();  // A: drains vmcnt -> mtile[mc] ready for all waves

      // PV B-frags for this chunk (global, read-once; hidden under S-phase)
      short8 bfT[2][2];
#pragma unroll
      for (int ct = 0; ct < 2; ++ct) {
        const unsigned short* tp =
            membT + (size_t)(w * 32 + ct * 16 + lm) * MP_ + mc * 64 + quad * 8;
        bfT[ct][0] = *(const short8*)(tp);
        bfT[ct][1] = *(const short8*)(tp + 32);
      }

      // ---- S = Q @ mem^T (rows 16rg.., m-half mh) from LDS frag-order tile ----
      floatx4 accS[2];
      accS[0] = (floatx4){0.f, 0.f, 0.f, 0.f};
      accS[1] = (floatx4){0.f, 0.f, 0.f, 0.f};
      __builtin_amdgcn_s_setprio(1);
#pragma unroll
      for (int mt2 = 0; mt2 < 2; ++mt2) {
        int mrow = mh * 32 + mt2 * 16 + lm;
#pragma unroll
        for (int kb = 0; kb < 8; ++kb) {
          short8 bf = *(const short8*)&mtile[(size_t)(((kb * 4 + quad) * 64) + mrow) * 8];
          accS[mt2] = __builtin_amdgcn_mfma_f32_16x16x32_bf16(afrag[kb], bf, accS[mt2], 0, 0, 0);
        }
      }
      __builtin_amdgcn_s_setprio(0);

      // ---- P = exp(S/T) bf16 (unnormalized; |logit|<=33.3), frag-order store ----
      unsigned short* P = (mc & 1) ? Pbuf1 : Pbuf0;
#pragma unroll
      for (int mt2 = 0; mt2 < 2; ++mt2) {
        int m = mh * 32 + mt2 * 16 + lm;
        // exp-mask bias: padding rows get exp(-1e30) = 0 (no select per elem);
        // valid rows: fma(S, IT, 0) == rn(S*IT) — bit-exact vs v4.
        float ebias = (mc * 64 + m < M_) ? 0.f : -1e30f;
        int g = mh * 4 + mt2 * 2 + (lm >> 3);
#pragma unroll
        for (int r = 0; r < 4; ++r) {
          float pv = __expf(__builtin_fmaf(accS[mt2][r], INV_TEMP, ebias));
          unsigned short pb = f2bf(pv);
          rs[r] += bf2f(pb);
          P[(g * 64 + 16 * rg + quad * 4 + r) * 8 + (lm & 7)] = pb;
        }
      }
      barrier_lds_only();  // B: P visible + mtile S-reads done (vmcnt NOT drained)

      // issue next chunk's async stage (in flight across PV, lands before next A)
      if (mc + 1 < NCHUNK) stage_chunk(memS, mc + 1, mtile, w, l);

      // ---- O += P @ mem (this wave's 32-wide C-slice) ----
      __builtin_amdgcn_s_setprio(1);
#pragma unroll
      for (int rt = 0; rt < 4; ++rt) {
        short8 pf0 = *(const short8*)&P[(size_t)((0 + quad) * 64 + rt * 16 + lm) * 8];
        short8 pf1 = *(const short8*)&P[(size_t)((4 + quad) * 64 + rt * 16 + lm) * 8];
#pragma unroll
        for (int ct = 0; ct < 2; ++ct) {
          accO[rt][ct] = __builtin_amdgcn_mfma_f32_16x16x32_bf16(pf0, bfT[ct][0], accO[rt][ct], 0, 0, 0);
          accO[rt][ct] = __builtin_amdgcn_mfma_f32_16x16x32_bf16(pf1, bfT[ct][1], accO[rt][ct], 0, 0, 0);
        }
      }
      __builtin_amdgcn_s_setprio(0);
    }

    // ---- rowsum: intra-wave shuffle over lm, cross-wave LDS atomic ----
#pragma unroll
    for (int off = 1; off < 16; off <<= 1)
#pragma unroll
      for (int r = 0; r < 4; ++r) rs[r] += __shfl_xor(rs[r], off, 64);
    if (lm == 0) {
#pragma unroll
      for (int r = 0; r < 4; ++r) atomicAdd(&rowsum[16 * rg + quad * 4 + r], rs[r]);
    }
    __syncthreads();
    if (t < 64) comb[t] = gp[row0 + t] / rowsum[t];
    __syncthreads();

    // ---- epilogue (trans aliases mtile; no stage loads in flight here) ----
#pragma unroll 1
    for (int cg2 = 0; cg2 < 4; ++cg2) {
      if ((w >> 1) == cg2) {
#pragma unroll
        for (int rt = 0; rt < 4; ++rt)
#pragma unroll
          for (int r = 0; r < 4; ++r) {
            float cf = comb[16 * rt + quad * 4 + r];
#pragma unroll
            for (int ct = 0; ct < 2; ++ct)
              trans[(16 * rt + quad * 4 + r) * 67 + (w & 1) * 32 + ct * 16 + lm] =
                  cf * accO[rt][ct][r];
          }
      }
      __syncthreads();
      if (pass == 0) {
#pragma unroll
        for (int i = 0; i < 8; ++i) {
          int cl = w * 8 + i;
          int cg = cg2 * 64 + cl;
          out[ob + (size_t)cg * HW_] = trans[l * 67 + cl];  // out = alpha_f * O_f
        }
      } else {
#pragma unroll
        for (int i = 0; i < 8; ++i) {
          int cl = w * 8 + i;
          int cg = cg2 * 64 + cl;
          size_t a = ob + (size_t)cg * HW_;
          out[a] = feats[a] * iv + out[a] - trans[l * 67 + cl];
        }
      }
      __syncthreads();
    }
  }
}

extern "C" void kernel_launch(void* const* d_in, const int* in_sizes, int n_in,
                              void* d_out, int out_size, void* d_ws, size_t ws_size,
                              hipStream_t stream) {
  const float* feats = (const float*)d_in[0];
  const float* fg    = (const float*)d_in[1];
  const float* bg    = (const float*)d_in[2];
  const float* w1f   = (const float*)d_in[3];
  const float* b1f   = (const float*)d_in[4];
  const float* w2f   = (const float*)d_in[5];
  const float* b2f   = (const float*)d_in[6];
  const float* w1b   = (const float*)d_in[7];
  const float* b1b   = (const float*)d_in[8];
  const float* w2b   = (const float*)d_in[9];
  const float* b2b   = (const float*)d_in[10];
  float* out = (float*)d_out;

  char* ws = (char*)d_ws;
  unsigned short* xnb = (unsigned short*)ws;                 // N_*C_ bf16
  unsigned short* fgS = xnb + (size_t)N_ * C_;               // MP_*C_ (frag order)
  unsigned short* bgS = fgS + (size_t)MP_ * C_;
  unsigned short* fgT = bgS + (size_t)MP_ * C_;              // C_*MP_
  unsigned short* bgT = fgT + (size_t)C_ * MP_;
  float* gf   = (float*)(bgT + (size_t)C_ * MP_);            // N_
  float* gb   = gf + N_;                                     // N_
  float* invn = gb + N_;                                     // N_

  norm_mem_kernel<<<64, 256, 0, stream>>>(fg, bg, fgS, bgS, fgT, bgT);
  prep_x_kernel<<<N_ / 64, 256, 0, stream>>>(feats, invn, xnb);
  gate_kernel<<<N_ / 16, 256, 0, stream>>>(xnb, w1f, b1f, w2f, b2f,
                                           w1b, b1b, w2b, b2b, gf, gb);
  flash_fused_kernel<<<N_ / 64, 512, 0, stream>>>(
      xnb, fgS, fgT, bgS, bgT, gf, gb, feats, invn, out);
}